// Round 4
// baseline (290.653 us; speedup 1.0000x reference)
//
#include <hip/hip_runtime.h>
#include <math.h>

#define N 4096
#define D 512
#define NUM_STEPS 151
#define HALF_BINS 75
#define INV_STEP 75.0f
#define NUM_CLASSES 751
#define P_TOTAL 8386560.0f   // N*(N-1)/2, exact in fp32 (< 2^24)

// ws layout (float indices into d_ws)
#define WS_SUM_ALL 0
#define WS_POS_CNT 1          // int
#define WS_SUM_POS 2
#define WS_S_POS   3
#define WS_G_OFF   8          // 151 floats
#define WS_LIST_OFF 1024
#define MAXP (1 << 18)        // 262144-entry pos-sim list (expect ~11K)
#define WS_FEAT_OFF (WS_LIST_OFF + MAXP)          // 4096x512 fp32 normalized feats
#define WS_FEATB_OFF (WS_FEAT_OFF + N * D)        // 4096x512 bf16 normalized feats (N*D/2 floats)
#define WS_IDX_OFF  (WS_FEATB_OFF + N * D / 2)    // N ints: row indices grouped by class
#define WS_OFFS_OFF (WS_IDX_OFF + N)              // NUM_CLASSES+1 ints: class offsets

typedef __bf16 bf16x8 __attribute__((ext_vector_type(8)));
typedef float floatx4 __attribute__((ext_vector_type(4)));

// ---------------- K1: row L2-normalize (fp32 + bf16 outputs) ----------------
__global__ __launch_bounds__(256) void k_normalize(const float* __restrict__ feat,
                                                   float* __restrict__ nf,
                                                   __bf16* __restrict__ nfb) {
    int row = blockIdx.x;
    int t = threadIdx.x;
    const float* fr = feat + (size_t)row * D;
    float a = fr[t];
    float b = fr[t + 256];
    float ss = a * a + b * b;
    for (int o = 32; o > 0; o >>= 1) ss += __shfl_down(ss, o, 64);
    __shared__ float wsum[4];
    int lane = t & 63, wid = t >> 6;
    if (lane == 0) wsum[wid] = ss;
    __syncthreads();
    float tot = wsum[0] + wsum[1] + wsum[2] + wsum[3];
    float inv = 1.0f / sqrtf(tot);
    float na = a * inv, nb = b * inv;
    nf[(size_t)row * D + t] = na;
    nf[(size_t)row * D + t + 256] = nb;
    nfb[(size_t)row * D + t] = (__bf16)na;
    nfb[(size_t)row * D + t + 256] = (__bf16)nb;
}

// ---------------- K2a: group row indices by class (counting sort, 1 block) ----------------
__global__ __launch_bounds__(256) void k_sort(const int* __restrict__ cls,
                                              int* __restrict__ rowIdx,
                                              int* __restrict__ offs) {
    __shared__ int hcnt[NUM_CLASSES];
    __shared__ int hoff[NUM_CLASSES + 1];
    int t = threadIdx.x;
    for (int c = t; c < NUM_CLASSES; c += 256) hcnt[c] = 0;
    __syncthreads();
    for (int n = t; n < N; n += 256) atomicAdd(&hcnt[cls[n]], 1);
    __syncthreads();
    if (t == 0) {
        int acc = 0;
        for (int c = 0; c < NUM_CLASSES; ++c) { hoff[c] = acc; acc += hcnt[c]; }
        hoff[NUM_CLASSES] = acc;
    }
    __syncthreads();
    for (int c = t; c < NUM_CLASSES; c += 256) hcnt[c] = hoff[c];   // cursors
    __syncthreads();
    for (int n = t; n < N; n += 256) {
        int p = atomicAdd(&hcnt[cls[n]], 1);
        rowIdx[p] = n;
    }
    for (int c = t; c < NUM_CLASSES + 1; c += 256) offs[c] = hoff[c];
}

// ---------------- K2b: within-class pair similarities (1 block per class) ----------------
__global__ __launch_bounds__(256) void k_pospairs2(const float* __restrict__ nf,
                                                   const int* __restrict__ rowIdx,
                                                   const int* __restrict__ offs,
                                                   float* __restrict__ posS,
                                                   int* __restrict__ posCnt) {
    int c = blockIdx.x;
    int o0 = offs[c], o1 = offs[c + 1];
    int nc = o1 - o0;
    if (nc < 2) return;
    int nPairs = nc * (nc - 1) / 2;
    int lane = threadIdx.x & 63;
    int wave = threadIdx.x >> 6;
    for (int p = wave; p < nPairs; p += 4) {
        // decode pair p -> (a, b), a < b
        int a = 0, rem = p;
        while (rem >= nc - 1 - a) { rem -= nc - 1 - a; ++a; }
        int b = a + 1 + rem;
        int ri = rowIdx[o0 + a], rj = rowIdx[o0 + b];
        const float4* x4 = (const float4*)(nf + (size_t)ri * D);
        const float4* y4 = (const float4*)(nf + (size_t)rj * D);
        // lane covers dims [8*lane, 8*lane+8): two float4 loads each
        float4 xa = x4[lane * 2], xb = x4[lane * 2 + 1];
        float4 ya = y4[lane * 2], yb = y4[lane * 2 + 1];
        float s = xa.x * ya.x + xa.y * ya.y + xa.z * ya.z + xa.w * ya.w
                + xb.x * yb.x + xb.y * yb.y + xb.z * yb.z + xb.w * yb.w;
        for (int o = 32; o > 0; o >>= 1) s += __shfl_down(s, o, 64);
        if (lane == 0) {
            int idx = atomicAdd(posCnt, 1);
            if (idx < MAXP) posS[idx] = s;
        }
    }
}

// ---------------- K3: hist_pos -> cdf -> G table, plus sum_pos g ----------------
__global__ __launch_bounds__(256) void k_build_cdf(const float* __restrict__ posS,
                                                   const int* __restrict__ posCnt,
                                                   float* __restrict__ G,
                                                   float* __restrict__ sumPosOut,
                                                   float* __restrict__ sPosOut) {
    __shared__ float hist[NUM_STEPS];
    __shared__ float Gs[NUM_STEPS];
    int t = threadIdx.x;
    int C = *posCnt;
    if (C > MAXP) C = MAXP;
    for (int b = t; b < NUM_STEPS; b += 256) hist[b] = 0.f;
    __syncthreads();
    for (int p = t; p < C; p += 256) {
        float s = posS[p];
        float x = s * INV_STEP;
        float kf = floorf(x);
        float frac = x - kf;
        int kI = (int)kf;
        int lo = min(max(kI + HALF_BINS, 0), NUM_STEPS - 1);
        int hi = min(max(kI + HALF_BINS + 1, 0), NUM_STEPS - 1);
        atomicAdd(&hist[lo], 1.0f - frac);
        atomicAdd(&hist[hi], frac);
    }
    __syncthreads();
    if (t == 0) {
        float invC = (C > 0) ? (1.0f / (float)C) : 0.f;
        float acc = 0.f;
        for (int b = 0; b < NUM_STEPS; ++b) {
            acc += hist[b];
            Gs[b] = acc * invC;
        }
    }
    __syncthreads();
    for (int b = t; b < NUM_STEPS; b += 256) G[b] = Gs[b];
    float ps = 0.f;
    for (int p = t; p < C; p += 256) {
        float s = posS[p];
        float x = s * INV_STEP;
        float kf = floorf(x);
        float frac = x - kf;
        int kI = (int)kf;
        int lo = min(max(kI + HALF_BINS, 0), NUM_STEPS - 1);
        int hi = min(max(kI + HALF_BINS + 1, 0), NUM_STEPS - 1);
        ps += (1.f - frac) * Gs[lo] + frac * Gs[hi];
    }
    for (int o = 32; o > 0; o >>= 1) ps += __shfl_down(ps, o, 64);
    __shared__ float wsum[4];
    int lane = t & 63, wid = t >> 6;
    if (lane == 0) wsum[wid] = ps;
    __syncthreads();
    if (t == 0) {
        *sumPosOut = wsum[0] + wsum[1] + wsum[2] + wsum[3];
        *sPosOut = (float)C;
    }
}

// ---------------- K4: upper-tri 128x128 MFMA Gram + g-lookup accumulate ----------------
#define TILES_1D 32            // 4096 / 128
#define LDSS 40                // LDS row stride in bf16 (32 + 8 pad; 80B, 2-way bank alias = free)

__global__ __launch_bounds__(256) void k_gram(const __bf16* __restrict__ nfb,
                                              const float* __restrict__ G,
                                              float* __restrict__ sumAll) {
    // map linear block id -> upper-tri tile (ti, tj), tj >= ti
    int bid = blockIdx.x;
    int ti = 0, rem = bid;
    while (rem >= TILES_1D - ti) { rem -= TILES_1D - ti; ++ti; }
    int tj = ti + rem;

    __shared__ __align__(16) __bf16 As[128 * LDSS];
    __shared__ __align__(16) __bf16 Bs[128 * LDSS];
    __shared__ float Gs[NUM_STEPS];

    int tid = threadIdx.x;
    for (int b = tid; b < NUM_STEPS; b += 256) Gs[b] = G[b];

    int lane = tid & 63;
    int wave = tid >> 6;
    int wm = (wave >> 1) * 64;   // wave's 64-row region in A
    int wn = (wave & 1) * 64;    // wave's 64-row region in B
    int fr = lane & 15;          // row within 16 (A-row / B-row)
    int fk = (lane >> 4) * 8;    // k offset within BK

    int rowA0 = ti * 128, rowB0 = tj * 128;

    floatx4 acc[4][4] = {};

    // staging decomposition: 2 chunks of 8 bf16 per thread per matrix
    int e0 = tid * 8;            // chunk 0 element index (of 4096)
    int e1 = e0 + 2048;          // chunk 1
    int r0 = e0 >> 5, c0 = e0 & 31;
    int r1 = e1 >> 5, c1 = e1 & 31;

    for (int kb = 0; kb < D / 32; ++kb) {
        int kbase = kb * 32;
        // stage A and B tiles: 128 rows x 32 bf16, 16B vector loads
        *(float4*)(&As[r0 * LDSS + c0]) = *(const float4*)(nfb + (size_t)(rowA0 + r0) * D + kbase + c0);
        *(float4*)(&As[r1 * LDSS + c1]) = *(const float4*)(nfb + (size_t)(rowA0 + r1) * D + kbase + c1);
        *(float4*)(&Bs[r0 * LDSS + c0]) = *(const float4*)(nfb + (size_t)(rowB0 + r0) * D + kbase + c0);
        *(float4*)(&Bs[r1 * LDSS + c1]) = *(const float4*)(nfb + (size_t)(rowB0 + r1) * D + kbase + c1);
        __syncthreads();

        bf16x8 a[4], b[4];
        #pragma unroll
        for (int r = 0; r < 4; ++r)
            a[r] = *(const bf16x8*)(&As[(wm + r * 16 + fr) * LDSS + fk]);
        #pragma unroll
        for (int c = 0; c < 4; ++c)
            b[c] = *(const bf16x8*)(&Bs[(wn + c * 16 + fr) * LDSS + fk]);

        #pragma unroll
        for (int r = 0; r < 4; ++r)
            #pragma unroll
            for (int c = 0; c < 4; ++c)
                acc[r][c] = __builtin_amdgcn_mfma_f32_16x16x32_bf16(a[r], b[c], acc[r][c], 0, 0, 0);
        __syncthreads();
    }

    // epilogue: g(s) lookup with upper-triangle mask
    // C/D layout (16x16x32): col = lane&15 (B index), row = (lane>>4)*4 + reg (A index)
    int crow = (lane >> 4) * 4;
    int ccol = lane & 15;
    float gsum = 0.f;
    #pragma unroll
    for (int r = 0; r < 4; ++r) {
        #pragma unroll
        for (int c = 0; c < 4; ++c) {
            #pragma unroll
            for (int reg = 0; reg < 4; ++reg) {
                int gi = rowA0 + wm + r * 16 + crow + reg;
                int gj = rowB0 + wn + c * 16 + ccol;
                if (gi < gj) {
                    float s = acc[r][c][reg];
                    float x = s * INV_STEP;
                    float kf = floorf(x);
                    float frac = x - kf;
                    int kI = (int)kf;
                    int lo = min(max(kI + HALF_BINS, 0), NUM_STEPS - 1);
                    int hi = min(max(kI + HALF_BINS + 1, 0), NUM_STEPS - 1);
                    gsum += (1.f - frac) * Gs[lo] + frac * Gs[hi];
                }
            }
        }
    }
    for (int o = 32; o > 0; o >>= 1) gsum += __shfl_down(gsum, o, 64);
    __shared__ float wsum[4];
    if ((tid & 63) == 0) wsum[tid >> 6] = gsum;
    __syncthreads();
    if (tid == 0) atomicAdd(sumAll, wsum[0] + wsum[1] + wsum[2] + wsum[3]);
}

// ---------------- K5: final combine ----------------
__global__ void k_final(const float* __restrict__ wsf, float* __restrict__ out) {
    float C = wsf[WS_S_POS];
    float sneg = P_TOTAL - C;
    out[0] = (wsf[WS_SUM_ALL] - wsf[WS_SUM_POS]) / sneg;
}

extern "C" void kernel_launch(void* const* d_in, const int* in_sizes, int n_in,
                              void* d_out, int out_size, void* d_ws, size_t ws_size,
                              hipStream_t stream) {
    const float* feat = (const float*)d_in[0];
    const int* cls = (const int*)d_in[1];
    float* out = (float*)d_out;
    float* wsf = (float*)d_ws;
    int* wsi = (int*)d_ws;

    // zero the accumulator / counter / G header region
    hipMemsetAsync(d_ws, 0, 4096, stream);

    float* nf = wsf + WS_FEAT_OFF;
    __bf16* nfb = (__bf16*)(wsf + WS_FEATB_OFF);
    float* posS = wsf + WS_LIST_OFF;
    float* G = wsf + WS_G_OFF;
    int* rowIdx = wsi + WS_IDX_OFF;
    int* offs = wsi + WS_OFFS_OFF;

    k_normalize<<<N, 256, 0, stream>>>(feat, nf, nfb);
    k_sort<<<1, 256, 0, stream>>>(cls, rowIdx, offs);
    k_pospairs2<<<NUM_CLASSES, 256, 0, stream>>>(nf, rowIdx, offs, posS, wsi + WS_POS_CNT);
    k_build_cdf<<<1, 256, 0, stream>>>(posS, wsi + WS_POS_CNT, G,
                                       wsf + WS_SUM_POS, wsf + WS_S_POS);
    int nTiles = TILES_1D * (TILES_1D + 1) / 2;   // 528 upper-tri 128x128 tiles
    k_gram<<<nTiles, 256, 0, stream>>>(nfb, G, wsf + WS_SUM_ALL);
    k_final<<<1, 1, 0, stream>>>(wsf, out);
}

// Round 5
// 159.833 us; speedup vs baseline: 1.8185x; 1.8185x over previous
//
#include <hip/hip_runtime.h>
#include <math.h>

#define N 4096
#define D 512
#define NUM_STEPS 151
#define HALF_BINS 75
#define INV_STEP 75.0f
#define NUM_CLASSES 751
#define P_TOTAL 8386560.0f   // N*(N-1)/2, exact in fp32 (< 2^24)

// ws layout (float indices into d_ws)
#define WS_SUM_ALL 0
#define WS_POS_CNT 1          // int (total pos pairs, written by k_sort)
#define WS_SUM_POS 2
#define WS_S_POS   3
#define WS_G_OFF   8          // 151 floats
#define WS_LIST_OFF 1024
#define MAXP (1 << 18)        // 262144-entry pos-sim list (expect ~11K)
#define WS_FEAT_OFF (WS_LIST_OFF + MAXP)          // 4096x512 fp32 normalized feats
#define WS_FEATB_OFF (WS_FEAT_OFF + N * D)        // 4096x512 bf16 normalized feats (N*D/2 floats)
#define WS_IDX_OFF  (WS_FEATB_OFF + N * D / 2)    // N ints: row indices grouped by class
#define WS_OFFS_OFF (WS_IDX_OFF + N)              // NUM_CLASSES+1 ints: class row offsets
#define WS_POFF_OFF (WS_OFFS_OFF + NUM_CLASSES + 1) // NUM_CLASSES+1 ints: class pair offsets

typedef __bf16 bf16x8 __attribute__((ext_vector_type(8)));
typedef float floatx4 __attribute__((ext_vector_type(4)));

// ---------------- K1: row L2-normalize (fp32 + bf16 outputs) ----------------
__global__ __launch_bounds__(256) void k_normalize(const float* __restrict__ feat,
                                                   float* __restrict__ nf,
                                                   __bf16* __restrict__ nfb) {
    int row = blockIdx.x;
    int t = threadIdx.x;
    const float* fr = feat + (size_t)row * D;
    float a = fr[t];
    float b = fr[t + 256];
    float ss = a * a + b * b;
    for (int o = 32; o > 0; o >>= 1) ss += __shfl_down(ss, o, 64);
    __shared__ float wsum[4];
    int lane = t & 63, wid = t >> 6;
    if (lane == 0) wsum[wid] = ss;
    __syncthreads();
    float tot = wsum[0] + wsum[1] + wsum[2] + wsum[3];
    float inv = 1.0f / sqrtf(tot);
    float na = a * inv, nb = b * inv;
    nf[(size_t)row * D + t] = na;
    nf[(size_t)row * D + t + 256] = nb;
    nfb[(size_t)row * D + t] = (__bf16)na;
    nfb[(size_t)row * D + t + 256] = (__bf16)nb;
}

// ---------------- K2a: counting sort + prefix sums (rows AND pair slots) ----------------
// 256 threads; each owns up to 3 classes (751 <= 768). Parallel shfl scan -> no
// serial thread-0 prefix, and no global atomic counter downstream.
__global__ __launch_bounds__(256) void k_sort(const int* __restrict__ cls,
                                              int* __restrict__ rowIdx,
                                              int* __restrict__ offs,
                                              int* __restrict__ pairOffs,
                                              int* __restrict__ posCntOut) {
    __shared__ int hcnt[NUM_CLASSES];
    __shared__ int hoff[NUM_CLASSES];
    __shared__ int poff[NUM_CLASSES];
    __shared__ int wsumR[4], wsumP[4];
    int t = threadIdx.x;
    for (int c = t; c < NUM_CLASSES; c += 256) hcnt[c] = 0;
    __syncthreads();
    for (int n = t; n < N; n += 256) atomicAdd(&hcnt[cls[n]], 1);
    __syncthreads();

    // per-thread local sums over its 3 classes
    int c0 = t * 3;
    int cntPreR[3], cntPreP[3];
    int myR = 0, myP = 0;
    #pragma unroll
    for (int k = 0; k < 3; ++k) {
        int c = c0 + k;
        int cnt = (c < NUM_CLASSES) ? hcnt[c] : 0;
        cntPreR[k] = myR; cntPreP[k] = myP;       // exclusive-within-thread
        myR += cnt;
        myP += cnt * (cnt - 1) / 2;
    }
    // wave-level inclusive scan (64 lanes)
    int lane = t & 63, wv = t >> 6;
    int incR = myR, incP = myP;
    for (int o = 1; o < 64; o <<= 1) {
        int rr = __shfl_up(incR, o, 64);
        int pp = __shfl_up(incP, o, 64);
        if (lane >= o) { incR += rr; incP += pp; }
    }
    if (lane == 63) { wsumR[wv] = incR; wsumP[wv] = incP; }
    __syncthreads();
    int baseR = 0, baseP = 0;
    for (int w = 0; w < wv; ++w) { baseR += wsumR[w]; baseP += wsumP[w]; }
    int exR = baseR + incR - myR;                 // exclusive prefix for thread
    int exP = baseP + incP - myP;
    #pragma unroll
    for (int k = 0; k < 3; ++k) {
        int c = c0 + k;
        if (c < NUM_CLASSES) { hoff[c] = exR + cntPreR[k]; poff[c] = exP + cntPreP[k]; }
    }
    __syncthreads();

    // scatter rows grouped by class (LDS cursor atomics only)
    for (int c = t; c < NUM_CLASSES; c += 256) hcnt[c] = hoff[c];
    __syncthreads();
    for (int n = t; n < N; n += 256) {
        int p = atomicAdd(&hcnt[cls[n]], 1);
        rowIdx[p] = n;
    }
    for (int c = t; c < NUM_CLASSES; c += 256) { offs[c] = hoff[c]; pairOffs[c] = poff[c]; }
    if (t == 0) {
        int totR = wsumR[0] + wsumR[1] + wsumR[2] + wsumR[3];
        int totP = wsumP[0] + wsumP[1] + wsumP[2] + wsumP[3];
        offs[NUM_CLASSES] = totR;
        pairOffs[NUM_CLASSES] = totP;
        *posCntOut = totP;
    }
}

// ---------------- K2b: within-class pair sims, deterministic slots, NO atomics ----------------
__global__ __launch_bounds__(256) void k_pospairs3(const float* __restrict__ nf,
                                                   const int* __restrict__ rowIdx,
                                                   const int* __restrict__ offs,
                                                   const int* __restrict__ pairOffs,
                                                   float* __restrict__ posS) {
    int c = blockIdx.x;
    int o0 = offs[c], o1 = offs[c + 1];
    int nc = o1 - o0;
    if (nc < 2) return;
    int nPairs = nc * (nc - 1) / 2;
    int pBase = pairOffs[c];
    int lane = threadIdx.x & 63;
    int wave = threadIdx.x >> 6;
    for (int p = wave; p < nPairs; p += 4) {
        // decode pair p -> (a, b), a < b
        int a = 0, rem = p;
        while (rem >= nc - 1 - a) { rem -= nc - 1 - a; ++a; }
        int b = a + 1 + rem;
        int ri = rowIdx[o0 + a], rj = rowIdx[o0 + b];
        const float4* x4 = (const float4*)(nf + (size_t)ri * D);
        const float4* y4 = (const float4*)(nf + (size_t)rj * D);
        float4 xa = x4[lane * 2], xb = x4[lane * 2 + 1];
        float4 ya = y4[lane * 2], yb = y4[lane * 2 + 1];
        float s = xa.x * ya.x + xa.y * ya.y + xa.z * ya.z + xa.w * ya.w
                + xb.x * yb.x + xb.y * yb.y + xb.z * yb.z + xb.w * yb.w;
        for (int o = 32; o > 0; o >>= 1) s += __shfl_down(s, o, 64);
        if (lane == 0) posS[pBase + p] = s;       // deterministic slot, fire-and-forget
    }
}

// ---------------- K3: hist_pos -> cdf -> G table, plus sum_pos g ----------------
__global__ __launch_bounds__(256) void k_build_cdf(const float* __restrict__ posS,
                                                   const int* __restrict__ posCnt,
                                                   float* __restrict__ G,
                                                   float* __restrict__ sumPosOut,
                                                   float* __restrict__ sPosOut) {
    __shared__ float hist[NUM_STEPS];
    __shared__ float Gs[NUM_STEPS];
    int t = threadIdx.x;
    int C = *posCnt;
    if (C > MAXP) C = MAXP;
    for (int b = t; b < NUM_STEPS; b += 256) hist[b] = 0.f;
    __syncthreads();
    for (int p = t; p < C; p += 256) {
        float s = posS[p];
        float x = s * INV_STEP;
        float kf = floorf(x);
        float frac = x - kf;
        int kI = (int)kf;
        int lo = min(max(kI + HALF_BINS, 0), NUM_STEPS - 1);
        int hi = min(max(kI + HALF_BINS + 1, 0), NUM_STEPS - 1);
        atomicAdd(&hist[lo], 1.0f - frac);
        atomicAdd(&hist[hi], frac);
    }
    __syncthreads();
    if (t == 0) {
        float invC = (C > 0) ? (1.0f / (float)C) : 0.f;
        float acc = 0.f;
        for (int b = 0; b < NUM_STEPS; ++b) {
            acc += hist[b];
            Gs[b] = acc * invC;
        }
    }
    __syncthreads();
    for (int b = t; b < NUM_STEPS; b += 256) G[b] = Gs[b];
    float ps = 0.f;
    for (int p = t; p < C; p += 256) {
        float s = posS[p];
        float x = s * INV_STEP;
        float kf = floorf(x);
        float frac = x - kf;
        int kI = (int)kf;
        int lo = min(max(kI + HALF_BINS, 0), NUM_STEPS - 1);
        int hi = min(max(kI + HALF_BINS + 1, 0), NUM_STEPS - 1);
        ps += (1.f - frac) * Gs[lo] + frac * Gs[hi];
    }
    for (int o = 32; o > 0; o >>= 1) ps += __shfl_down(ps, o, 64);
    __shared__ float wsum[4];
    int lane = t & 63, wid = t >> 6;
    if (lane == 0) wsum[wid] = ps;
    __syncthreads();
    if (t == 0) {
        *sumPosOut = wsum[0] + wsum[1] + wsum[2] + wsum[3];
        *sPosOut = (float)C;
    }
}

// ---------------- K4: upper-tri 128x128 MFMA Gram + g-lookup accumulate ----------------
#define TILES_1D 32            // 4096 / 128
#define LDSS 40                // LDS row stride in bf16 (32 + 8 pad; 80B, 2-way bank alias = free)

__global__ __launch_bounds__(256) void k_gram(const __bf16* __restrict__ nfb,
                                              const float* __restrict__ G,
                                              float* __restrict__ sumAll) {
    // map linear block id -> upper-tri tile (ti, tj), tj >= ti
    int bid = blockIdx.x;
    int ti = 0, rem = bid;
    while (rem >= TILES_1D - ti) { rem -= TILES_1D - ti; ++ti; }
    int tj = ti + rem;

    __shared__ __align__(16) __bf16 As[128 * LDSS];
    __shared__ __align__(16) __bf16 Bs[128 * LDSS];
    __shared__ float Gs[NUM_STEPS];

    int tid = threadIdx.x;
    for (int b = tid; b < NUM_STEPS; b += 256) Gs[b] = G[b];

    int lane = tid & 63;
    int wave = tid >> 6;
    int wm = (wave >> 1) * 64;   // wave's 64-row region in A
    int wn = (wave & 1) * 64;    // wave's 64-row region in B
    int fr = lane & 15;          // row within 16 (A-row / B-row)
    int fk = (lane >> 4) * 8;    // k offset within BK

    int rowA0 = ti * 128, rowB0 = tj * 128;

    floatx4 acc[4][4] = {};

    // staging decomposition: 2 chunks of 8 bf16 per thread per matrix
    int e0 = tid * 8;            // chunk 0 element index (of 4096)
    int e1 = e0 + 2048;          // chunk 1
    int r0 = e0 >> 5, c0 = e0 & 31;
    int r1 = e1 >> 5, c1 = e1 & 31;

    for (int kb = 0; kb < D / 32; ++kb) {
        int kbase = kb * 32;
        // stage A and B tiles: 128 rows x 32 bf16, 16B vector loads
        *(float4*)(&As[r0 * LDSS + c0]) = *(const float4*)(nfb + (size_t)(rowA0 + r0) * D + kbase + c0);
        *(float4*)(&As[r1 * LDSS + c1]) = *(const float4*)(nfb + (size_t)(rowA0 + r1) * D + kbase + c1);
        *(float4*)(&Bs[r0 * LDSS + c0]) = *(const float4*)(nfb + (size_t)(rowB0 + r0) * D + kbase + c0);
        *(float4*)(&Bs[r1 * LDSS + c1]) = *(const float4*)(nfb + (size_t)(rowB0 + r1) * D + kbase + c1);
        __syncthreads();

        bf16x8 a[4], b[4];
        #pragma unroll
        for (int r = 0; r < 4; ++r)
            a[r] = *(const bf16x8*)(&As[(wm + r * 16 + fr) * LDSS + fk]);
        #pragma unroll
        for (int c = 0; c < 4; ++c)
            b[c] = *(const bf16x8*)(&Bs[(wn + c * 16 + fr) * LDSS + fk]);

        #pragma unroll
        for (int r = 0; r < 4; ++r)
            #pragma unroll
            for (int c = 0; c < 4; ++c)
                acc[r][c] = __builtin_amdgcn_mfma_f32_16x16x32_bf16(a[r], b[c], acc[r][c], 0, 0, 0);
        __syncthreads();
    }

    // epilogue: g(s) lookup with upper-triangle mask
    // C/D layout (16x16x32): col = lane&15 (B index), row = (lane>>4)*4 + reg (A index)
    int crow = (lane >> 4) * 4;
    int ccol = lane & 15;
    float gsum = 0.f;
    #pragma unroll
    for (int r = 0; r < 4; ++r) {
        #pragma unroll
        for (int c = 0; c < 4; ++c) {
            #pragma unroll
            for (int reg = 0; reg < 4; ++reg) {
                int gi = rowA0 + wm + r * 16 + crow + reg;
                int gj = rowB0 + wn + c * 16 + ccol;
                if (gi < gj) {
                    float s = acc[r][c][reg];
                    float x = s * INV_STEP;
                    float kf = floorf(x);
                    float frac = x - kf;
                    int kI = (int)kf;
                    int lo = min(max(kI + HALF_BINS, 0), NUM_STEPS - 1);
                    int hi = min(max(kI + HALF_BINS + 1, 0), NUM_STEPS - 1);
                    gsum += (1.f - frac) * Gs[lo] + frac * Gs[hi];
                }
            }
        }
    }
    for (int o = 32; o > 0; o >>= 1) gsum += __shfl_down(gsum, o, 64);
    __shared__ float wsum[4];
    if ((tid & 63) == 0) wsum[tid >> 6] = gsum;
    __syncthreads();
    if (tid == 0) atomicAdd(sumAll, wsum[0] + wsum[1] + wsum[2] + wsum[3]);
}

// ---------------- K5: final combine ----------------
__global__ void k_final(const float* __restrict__ wsf, float* __restrict__ out) {
    float C = wsf[WS_S_POS];
    float sneg = P_TOTAL - C;
    out[0] = (wsf[WS_SUM_ALL] - wsf[WS_SUM_POS]) / sneg;
}

extern "C" void kernel_launch(void* const* d_in, const int* in_sizes, int n_in,
                              void* d_out, int out_size, void* d_ws, size_t ws_size,
                              hipStream_t stream) {
    const float* feat = (const float*)d_in[0];
    const int* cls = (const int*)d_in[1];
    float* out = (float*)d_out;
    float* wsf = (float*)d_ws;
    int* wsi = (int*)d_ws;

    // zero the accumulator / counter / G header region
    hipMemsetAsync(d_ws, 0, 4096, stream);

    float* nf = wsf + WS_FEAT_OFF;
    __bf16* nfb = (__bf16*)(wsf + WS_FEATB_OFF);
    float* posS = wsf + WS_LIST_OFF;
    float* G = wsf + WS_G_OFF;
    int* rowIdx = wsi + WS_IDX_OFF;
    int* offs = wsi + WS_OFFS_OFF;
    int* pairOffs = wsi + WS_POFF_OFF;

    k_normalize<<<N, 256, 0, stream>>>(feat, nf, nfb);
    k_sort<<<1, 256, 0, stream>>>(cls, rowIdx, offs, pairOffs, wsi + WS_POS_CNT);
    k_pospairs3<<<NUM_CLASSES, 256, 0, stream>>>(nf, rowIdx, offs, pairOffs, posS);
    k_build_cdf<<<1, 256, 0, stream>>>(posS, wsi + WS_POS_CNT, G,
                                       wsf + WS_SUM_POS, wsf + WS_S_POS);
    int nTiles = TILES_1D * (TILES_1D + 1) / 2;   // 528 upper-tri 128x128 tiles
    k_gram<<<nTiles, 256, 0, stream>>>(nfb, G, wsf + WS_SUM_ALL);
    k_final<<<1, 1, 0, stream>>>(wsf, out);
}